// Round 13
// baseline (355.702 us; speedup 1.0000x reference)
//
#include <hip/hip_runtime.h>
#include <hip/hip_fp16.h>
#include <cstdint>
#include <cstddef>

// ---------------------------------------------------------------------------
// 2-layer GCN (PyG GCNConv semantics) on MI355X.
// Round 13: src-ordered adjacency for L2 phase-locality. New k_part0 buckets
// edges by SRC; k_part1 consumes it in order -> per-node CSR lists come out
// ~src-ascending. Gathers use persistent grid (2048 blocks) so resident waves
// sweep the same few-MB src window together (L2-resident), cutting TCC fill.
// ---------------------------------------------------------------------------

#define BSHIFT 8          // 256 nodes per bucket
#define CAP    12288      // window capacity per bucket (mean 8184, sd ~90)

typedef _Float16 half8 __attribute__((ext_vector_type(8)));
typedef float f32x4 __attribute__((ext_vector_type(4)));

// init both cursor arrays to window starts
__global__ __launch_bounds__(256) void k_binit2(int* __restrict__ cur0,
                                                int* __restrict__ cur1, int nbkt) {
  int b = blockIdx.x * 256 + threadIdx.x;
  if (b < nbkt) {
    cur0[b] = b * CAP;
    cur1[b] = b * CAP;
  }
}

// Pass 0: partition edges by SRC-bucket into part0 windows.
// Pack (dst<<8)|src_low (dst<2^24 ok).
__global__ __launch_bounds__(256) void k_part0(const int* __restrict__ src,
                                               const int* __restrict__ dst,
                                               int* __restrict__ cur0,
                                               int* __restrict__ part0, int E,
                                               int nbkt) {
  __shared__ int hist[512];
  const int tid = threadIdx.x;
  const int e0 = blockIdx.x * 4096;
  for (int b = tid; b < nbkt; b += 256) hist[b] = 0;
  __syncthreads();
#pragma unroll
  for (int j = 0; j < 16; ++j) {
    const int e = e0 + j * 256 + tid;
    if (e < E) atomicAdd(&hist[src[e] >> BSHIFT], 1);
  }
  __syncthreads();
  for (int b = tid; b < nbkt; b += 256) {
    const int c = hist[b];
    hist[b] = c ? atomicAdd(&cur0[b], c) : 0;  // becomes running cursor
  }
  __syncthreads();
#pragma unroll
  for (int j = 0; j < 16; ++j) {
    const int e = e0 + j * 256 + tid;
    if (e < E) {
      const int s = src[e];
      const int bkt = s >> BSHIFT;
      const int pos = atomicAdd(&hist[bkt], 1);
      if (pos < (bkt + 1) * CAP)
        part0[pos] = (dst[e] << BSHIFT) | (s & ((1 << BSHIFT) - 1));
    }
  }
}

// Pass 1: consume part0 in order (= approx src-ascending), partition by
// DST-bucket into part windows. Pack (src<<8)|dst_low.
__global__ __launch_bounds__(256) void k_part1(const int* __restrict__ part0,
                                               const int* __restrict__ cur0,
                                               int* __restrict__ bktcur,
                                               int* __restrict__ part, int nbkt) {
  __shared__ int hist[512];
  const int tid = threadIdx.x;
  const int e0 = blockIdx.x * 4096;
  for (int b = tid; b < nbkt; b += 256) hist[b] = 0;
  __syncthreads();
  int fv[16];  // final packed value
  int db[16];  // dst bucket, -1 if invalid
#pragma unroll
  for (int j = 0; j < 16; ++j) {
    const int pos = e0 + j * 256 + tid;
    const int sb = pos / CAP;
    db[j] = -1;
    fv[j] = 0;
    if (sb < nbkt && pos < cur0[sb]) {
      const int p = __builtin_nontemporal_load(part0 + pos);
      const int d = p >> BSHIFT;
      const int s = (sb << BSHIFT) | (p & ((1 << BSHIFT) - 1));
      fv[j] = (s << BSHIFT) | (d & ((1 << BSHIFT) - 1));
      db[j] = d >> BSHIFT;
      atomicAdd(&hist[db[j]], 1);
    }
  }
  __syncthreads();
  for (int b = tid; b < nbkt; b += 256) {
    const int c = hist[b];
    hist[b] = c ? atomicAdd(&bktcur[b], c) : 0;  // becomes running cursor
  }
  __syncthreads();
#pragma unroll
  for (int j = 0; j < 16; ++j) {
    if (db[j] >= 0) {
      const int pos = atomicAdd(&hist[db[j]], 1);
      if (pos < (db[j] + 1) * CAP) part[pos] = fv[j];
    }
  }
}

// Bucket bases: exclusive scan of (bktcur[b] - b*CAP). 1 block.
__global__ __launch_bounds__(256) void k_bktscan(const int* __restrict__ bktcur,
                                                 int* __restrict__ bktbase,
                                                 int* __restrict__ offsets, int n,
                                                 int E, int nbkt) {
  __shared__ int sc[512];
  const int t = threadIdx.x;
  sc[t] = (t < nbkt) ? (bktcur[t] - t * CAP) : 0;
  sc[256 + t] = (256 + t < nbkt) ? (bktcur[256 + t] - (256 + t) * CAP) : 0;
  __syncthreads();
  if (t == 0) {
    int run = 0;
    for (int b = 0; b < nbkt; ++b) {
      const int c = sc[b];
      sc[b] = run;
      run += c;
    }
    offsets[n] = E;
    bktbase[nbkt] = E;
  }
  __syncthreads();
  if (t < nbkt) bktbase[t] = sc[t];
  if (256 + t < nbkt) bktbase[256 + t] = sc[256 + t];
}

// Per bucket: LDS per-node count, LDS scan -> offsets + dinv, then STABLE
// compact scatter into final CSR slots (preserves ~src order within node).
__global__ __launch_bounds__(256) void k_csr2(const int* __restrict__ part,
                                              const int* __restrict__ bktcur,
                                              const int* __restrict__ bktbase,
                                              int* __restrict__ offsets,
                                              int* __restrict__ csr_src,
                                              float* __restrict__ dinv, int n) {
  __shared__ int cnt[256];
  __shared__ int ts[256];
  const int b = blockIdx.x;
  const int node0 = b << BSHIFT;
  const int nn = min(256, n - node0);
  const int t = threadIdx.x;
  cnt[t] = 0;
  __syncthreads();
  const int w0p = b * CAP;
  const int w1p = min(bktcur[b], w0p + CAP);
  for (int e = w0p + t; e < w1p; e += 256)
    atomicAdd(&cnt[part[e] & ((1 << BSHIFT) - 1)], 1);
  __syncthreads();
  const int c = cnt[t];
  ts[t] = c;
  __syncthreads();
  for (int off = 1; off < 256; off <<= 1) {
    const int u = (t >= off) ? ts[t - off] : 0;
    __syncthreads();
    ts[t] += u;
    __syncthreads();
  }
  const int excl = ts[t] - c;
  const int w0 = bktbase[b];
  if (t < nn) {
    offsets[node0 + t] = w0 + excl;
    dinv[node0 + t] = rsqrtf((float)c + 1.0f);
  }
  cnt[t] = w0 + excl;  // becomes cursor
  __syncthreads();
  // stable: sweep window in order; per 256-chunk, lanes scatter in index order
  for (int e = w0p + t; e < w1p; e += 256) {
    const int p = part[e];
    const int pos = atomicAdd(&cnt[p & ((1 << BSHIFT) - 1)], 1);
    csr_src[pos] = p >> BSHIFT;
  }
}

// ---------------------------------------------------------------------------
// MFMA fp16 GEMM: Hout[N,COLS](fp16) = (A[N,128] @ W[128,COLS]) * dinv[row].
// ---------------------------------------------------------------------------
template <typename TA, int COLS>
__global__ __launch_bounds__(256) void k_gemm_mfma(const TA* __restrict__ A,
                                                   const float* __restrict__ W,
                                                   const float* __restrict__ dinv,
                                                   __half* __restrict__ Hout,
                                                   int N, int ntiles) {
  constexpr int RW = (COLS == 128) ? 2 : 4;  // row-waves per tile
  constexpr int RPT = RW * 16;               // rows per tile
  __shared__ _Float16 Wt[128 * COLS];
  __shared__ _Float16 Lb[4][16][72];
  const int tid = threadIdx.x;
  const int w = tid >> 6;
  const int l = tid & 63;

  for (int f = tid; f < (128 * COLS) / 4; f += 256) {
    const int k = f / (COLS / 4);
    const int c4 = (f % (COLS / 4)) * 4;
    const float4 wv = *reinterpret_cast<const float4*>(W + (size_t)k * COLS + c4);
#pragma unroll
    for (int j = 0; j < 4; ++j) {
      const int cc = c4 + j;
      Wt[(cc * 128 + k) ^ ((cc & 7) << 3)] = (_Float16)(&wv.x)[j];
    }
  }
  __syncthreads();

  const int colw = (COLS == 128) ? (w >> 1) * 64 : 0;
  const int rw = (COLS == 128) ? (w & 1) : w;
  const int koff = (l >> 4) * 8;

  half8 bf[4][4];
#pragma unroll
  for (int t = 0; t < 4; ++t)
#pragma unroll
    for (int s = 0; s < 4; ++s) {
      const int cc = colw + 16 * t + (l & 15);
      const int kk = 32 * s + koff;
      bf[t][s] =
          *reinterpret_cast<const half8*>(&Wt[(cc * 128 + kk) ^ ((cc & 7) << 3)]);
    }

  for (int tile = blockIdx.x; tile < ntiles; tile += gridDim.x) {
    const int row = tile * RPT + rw * 16 + (l & 15);
    const int rowc = (row < N) ? row : (N - 1);
    f32x4 acc[4];
#pragma unroll
    for (int t = 0; t < 4; ++t) acc[t] = (f32x4){0.f, 0.f, 0.f, 0.f};

#pragma unroll
    for (int s = 0; s < 4; ++s) {
      half8 af;
      if constexpr (sizeof(TA) == 4) {
        const float* ap = (const float*)A + (size_t)rowc * 128 + 32 * s + koff;
        const float4 a0 = *reinterpret_cast<const float4*>(ap);
        const float4 a1 = *reinterpret_cast<const float4*>(ap + 4);
#pragma unroll
        for (int j = 0; j < 4; ++j) {
          af[j] = (_Float16)(&a0.x)[j];
          af[4 + j] = (_Float16)(&a1.x)[j];
        }
      } else {
        af = *reinterpret_cast<const half8*>((const __half*)A +
                                             (size_t)rowc * 128 + 32 * s + koff);
      }
#pragma unroll
      for (int t = 0; t < 4; ++t)
        acc[t] = __builtin_amdgcn_mfma_f32_16x16x32_f16(af, bf[t][s], acc[t],
                                                        0, 0, 0);
    }

    const int rbase = tile * RPT + rw * 16 + (l >> 4) * 4;
    float dr[4];
#pragma unroll
    for (int r = 0; r < 4; ++r) {
      const int rr = rbase + r;
      dr[r] = (rr < N) ? dinv[rr] : 0.f;
    }

#pragma unroll
    for (int t = 0; t < 4; ++t)
#pragma unroll
      for (int r = 0; r < 4; ++r)
        Lb[w][(l >> 4) * 4 + r][16 * t + (l & 15)] = (_Float16)(acc[t][r] * dr[r]);
    const int orow = tile * RPT + rw * 16 + (l & 15);
    if (orow < N) {
      const int ch = (l >> 4) * 16;
      const half8 v0 = *reinterpret_cast<const half8*>(&Lb[w][l & 15][ch]);
      const half8 v1 = *reinterpret_cast<const half8*>(&Lb[w][l & 15][ch + 8]);
      __half* hp = Hout + (size_t)orow * COLS + colw + ch;
      *reinterpret_cast<half8*>(hp) = v0;
      *reinterpret_cast<half8*>(hp + 8) = v1;
    }
  }
}

// ---------------------------------------------------------------------------
// Wide CSR gather over pre-scaled H (Hs = h*dinv, fp16), fp32 accumulate.
//   out[i] = relu( dinv[i] * (sum Hs[s] + Hs[i]) + bias )
// Persistent grid: all waves resident, phase-aligned over src-sorted lists.
// ---------------------------------------------------------------------------
__global__ __launch_bounds__(256) void k_gather128(
    const __half* __restrict__ H, const int* __restrict__ offsets,
    const int* __restrict__ csr_src, const float* __restrict__ dinv,
    const float* __restrict__ bias, __half* __restrict__ out, int N) {
  const int lane = threadIdx.x & 63;
  const int g = lane >> 3;  // 0..7 edge slot
  const int sl = lane & 7;  // 0..7 channel block (16 ch)
  int w = (blockIdx.x * 256 + threadIdx.x) >> 6;
  const int nw = (gridDim.x * 256) >> 6;
  for (int i = w; i < N; i += nw) {
    const int beg = offsets[i];
    const int end = offsets[i + 1];
    float acc[16];
    {
      const float vf = (g == 0) ? 1.f : 0.f;
      const float4 ha = *reinterpret_cast<const float4*>(H + (size_t)i * 128 + sl * 16);
      const float4 hb = *reinterpret_cast<const float4*>(H + (size_t)i * 128 + sl * 16 + 8);
      const __half2* pa = reinterpret_cast<const __half2*>(&ha);
      const __half2* pb = reinterpret_cast<const __half2*>(&hb);
#pragma unroll
      for (int q = 0; q < 4; ++q) {
        const float2 fa = __half22float2(pa[q]);
        const float2 fb = __half22float2(pb[q]);
        acc[q * 2] = vf * fa.x;
        acc[q * 2 + 1] = vf * fa.y;
        acc[8 + q * 2] = vf * fb.x;
        acc[8 + q * 2 + 1] = vf * fb.y;
      }
    }
    int base = beg;
    for (; base + 16 <= end; base += 16) {
      const int s0 = __builtin_nontemporal_load(csr_src + base + g);
      const int s1 = __builtin_nontemporal_load(csr_src + base + 8 + g);
      const float4 h0a = *reinterpret_cast<const float4*>(H + (size_t)s0 * 128 + sl * 16);
      const float4 h0b = *reinterpret_cast<const float4*>(H + (size_t)s0 * 128 + sl * 16 + 8);
      const float4 h1a = *reinterpret_cast<const float4*>(H + (size_t)s1 * 128 + sl * 16);
      const float4 h1b = *reinterpret_cast<const float4*>(H + (size_t)s1 * 128 + sl * 16 + 8);
      const __half2* p0a = reinterpret_cast<const __half2*>(&h0a);
      const __half2* p0b = reinterpret_cast<const __half2*>(&h0b);
      const __half2* p1a = reinterpret_cast<const __half2*>(&h1a);
      const __half2* p1b = reinterpret_cast<const __half2*>(&h1b);
#pragma unroll
      for (int q = 0; q < 4; ++q) {
        const float2 f0a = __half22float2(p0a[q]);
        const float2 f0b = __half22float2(p0b[q]);
        const float2 f1a = __half22float2(p1a[q]);
        const float2 f1b = __half22float2(p1b[q]);
        acc[q * 2] += f0a.x + f1a.x;
        acc[q * 2 + 1] += f0a.y + f1a.y;
        acc[8 + q * 2] += f0b.x + f1b.x;
        acc[8 + q * 2 + 1] += f0b.y + f1b.y;
      }
    }
    for (; base < end; base += 8) {
      const int e = base + g;
      const bool v = e < end;
      const int s = v ? __builtin_nontemporal_load(csr_src + e) : i;
      const float vf = v ? 1.f : 0.f;
      const float4 ha = *reinterpret_cast<const float4*>(H + (size_t)s * 128 + sl * 16);
      const float4 hb = *reinterpret_cast<const float4*>(H + (size_t)s * 128 + sl * 16 + 8);
      const __half2* pa = reinterpret_cast<const __half2*>(&ha);
      const __half2* pb = reinterpret_cast<const __half2*>(&hb);
#pragma unroll
      for (int q = 0; q < 4; ++q) {
        const float2 fa = __half22float2(pa[q]);
        const float2 fb = __half22float2(pb[q]);
        acc[q * 2] = fmaf(vf, fa.x, acc[q * 2]);
        acc[q * 2 + 1] = fmaf(vf, fa.y, acc[q * 2 + 1]);
        acc[8 + q * 2] = fmaf(vf, fb.x, acc[8 + q * 2]);
        acc[8 + q * 2 + 1] = fmaf(vf, fb.y, acc[8 + q * 2 + 1]);
      }
    }
#pragma unroll
    for (int j = 0; j < 16; ++j) {
      float a = acc[j];
      a += __shfl_xor(a, 8);
      a += __shfl_xor(a, 16);
      a += __shfl_xor(a, 32);
      acc[j] = a;
    }
    if (g == 0) {
      const float di = dinv[i];
      __half2 ov[8];
#pragma unroll
      for (int q = 0; q < 8; ++q) {
        const float2 bv = *reinterpret_cast<const float2*>(bias + sl * 16 + q * 2);
        ov[q] = __floats2half2_rn(fmaxf(fmaf(di, acc[q * 2], bv.x), 0.f),
                                  fmaxf(fmaf(di, acc[q * 2 + 1], bv.y), 0.f));
      }
      __half* op = out + (size_t)i * 128 + sl * 16;
      *reinterpret_cast<float4*>(op) = *reinterpret_cast<const float4*>(&ov[0]);
      *reinterpret_cast<float4*>(op + 8) = *reinterpret_cast<const float4*>(&ov[4]);
    }
  }
}

__global__ __launch_bounds__(256) void k_gather64(
    const __half* __restrict__ H, const int* __restrict__ offsets,
    const int* __restrict__ csr_src, const float* __restrict__ dinv,
    const float* __restrict__ bias, float* __restrict__ out, int N) {
  const int lane = threadIdx.x & 63;
  const int g = lane >> 3;  // 0..7 edge slot
  const int sl = lane & 7;  // 0..7 channel block (8 ch)
  int w = (blockIdx.x * 256 + threadIdx.x) >> 6;
  const int nw = (gridDim.x * 256) >> 6;
  for (int i = w; i < N; i += nw) {
    const int beg = offsets[i];
    const int end = offsets[i + 1];
    float acc[8];
    {
      const float vf = (g == 0) ? 1.f : 0.f;
      const float4 ha = *reinterpret_cast<const float4*>(H + (size_t)i * 64 + sl * 8);
      const __half2* pa = reinterpret_cast<const __half2*>(&ha);
#pragma unroll
      for (int q = 0; q < 4; ++q) {
        const float2 fa = __half22float2(pa[q]);
        acc[q * 2] = vf * fa.x;
        acc[q * 2 + 1] = vf * fa.y;
      }
    }
    int base = beg;
    for (; base + 16 <= end; base += 16) {
      const int s0 = __builtin_nontemporal_load(csr_src + base + g);
      const int s1 = __builtin_nontemporal_load(csr_src + base + 8 + g);
      const float4 h0 = *reinterpret_cast<const float4*>(H + (size_t)s0 * 64 + sl * 8);
      const float4 h1 = *reinterpret_cast<const float4*>(H + (size_t)s1 * 64 + sl * 8);
      const __half2* p0 = reinterpret_cast<const __half2*>(&h0);
      const __half2* p1 = reinterpret_cast<const __half2*>(&h1);
#pragma unroll
      for (int q = 0; q < 4; ++q) {
        const float2 f0 = __half22float2(p0[q]);
        const float2 f1 = __half22float2(p1[q]);
        acc[q * 2] += f0.x + f1.x;
        acc[q * 2 + 1] += f0.y + f1.y;
      }
    }
    for (; base < end; base += 8) {
      const int e = base + g;
      const bool v = e < end;
      const int s = v ? __builtin_nontemporal_load(csr_src + e) : i;
      const float vf = v ? 1.f : 0.f;
      const float4 ha = *reinterpret_cast<const float4*>(H + (size_t)s * 64 + sl * 8);
      const __half2* pa = reinterpret_cast<const __half2*>(&ha);
#pragma unroll
      for (int q = 0; q < 4; ++q) {
        const float2 fa = __half22float2(pa[q]);
        acc[q * 2] = fmaf(vf, fa.x, acc[q * 2]);
        acc[q * 2 + 1] = fmaf(vf, fa.y, acc[q * 2 + 1]);
      }
    }
#pragma unroll
    for (int j = 0; j < 8; ++j) {
      float a = acc[j];
      a += __shfl_xor(a, 8);
      a += __shfl_xor(a, 16);
      a += __shfl_xor(a, 32);
      acc[j] = a;
    }
    if (g == 0) {
      const float di = dinv[i];
      float* op = out + (size_t)i * 64 + sl * 8;
      const float4 b0 = *reinterpret_cast<const float4*>(bias + sl * 8);
      const float4 b1 = *reinterpret_cast<const float4*>(bias + sl * 8 + 4);
      float4 o;
      o.x = fmaxf(fmaf(di, acc[0], b0.x), 0.f);
      o.y = fmaxf(fmaf(di, acc[1], b0.y), 0.f);
      o.z = fmaxf(fmaf(di, acc[2], b0.z), 0.f);
      o.w = fmaxf(fmaf(di, acc[3], b0.w), 0.f);
      *reinterpret_cast<float4*>(op) = o;
      o.x = fmaxf(fmaf(di, acc[4], b1.x), 0.f);
      o.y = fmaxf(fmaf(di, acc[5], b1.y), 0.f);
      o.z = fmaxf(fmaf(di, acc[6], b1.z), 0.f);
      o.w = fmaxf(fmaf(di, acc[7], b1.w), 0.f);
      *reinterpret_cast<float4*>(op + 4) = o;
    }
  }
}

extern "C" void kernel_launch(void* const* d_in, const int* in_sizes, int n_in,
                              void* d_out, int out_size, void* d_ws,
                              size_t ws_size, hipStream_t stream) {
  const float* x  = (const float*)d_in[0];
  const int*   ei = (const int*)d_in[1];
  const float* W1 = (const float*)d_in[2];
  const float* b1 = (const float*)d_in[3];
  const float* W2 = (const float*)d_in[4];
  const float* b2 = (const float*)d_in[5];

  const int IN  = 128;
  const int n   = in_sizes[0] / IN;   // 100000
  const int E   = in_sizes[1] / 2;    // 3200000
  const int* srcv = ei;
  const int* dstv = ei + E;
  float* out = (float*)d_out;

  const int NBKT = (n + 255) >> BSHIFT;              // buckets (391)
  const int NCHK = (E + 4095) / 4096;                // pass-0 chunks (782)
  const int NP1  = (NBKT * CAP + 4095) / 4096;       // pass-1 chunks (1173)
  const int NT1  = (n + 31) / 32;                    // layer-1 tiles (3125)
  const int NT2  = (n + 63) / 64;                    // layer-2 tiles (1563)

  // Workspace (~65 MB): part0 aliases H16, part1 aliases hprime.
  char* p = (char*)d_ws;
  auto take = [&](size_t bytes) {
    char* r = p;
    p += (bytes + 255) & ~(size_t)255;
    return r;
  };
  float*  dinv    = (float*)take((size_t)n * 4);
  int*    offsets = (int*)take((size_t)(n + 1) * 4);
  int*    bktbase = (int*)take(512 * 4);
  int*    bktcur  = (int*)take(512 * 4);
  int*    bktcur0 = (int*)take(512 * 4);
  int*    csr_src = (int*)take((size_t)E * 4);            // 12.8 MB
  __half* H16     = (__half*)take((size_t)n * 128 * 2);   // 25.6 MB
  __half* hprime  = (__half*)take((size_t)n * 128 * 2);   // 25.6 MB
  int*    part0   = (int*)H16;                            // 19.2 MB alias
  int*    part    = (int*)hprime;                         // 19.2 MB alias

  // --- CSR build with src-ordered adjacency ---
  k_binit2<<<(NBKT + 255) / 256, 256, 0, stream>>>(bktcur0, bktcur, NBKT);
  k_part0<<<NCHK, 256, 0, stream>>>(srcv, dstv, bktcur0, part0, E, NBKT);
  k_part1<<<NP1, 256, 0, stream>>>(part0, bktcur0, bktcur, part, NBKT);
  k_bktscan<<<1, 256, 0, stream>>>(bktcur, bktbase, offsets, n, E, NBKT);
  k_csr2<<<NBKT, 256, 0, stream>>>(part, bktcur, bktbase, offsets, csr_src,
                                   dinv, n);

  // --- layer 1: H1s = (x@W1)*dinv (fp16) ; gather -> h' (fp16) ---
  k_gemm_mfma<float, 128><<<512, 256, 0, stream>>>(x, W1, dinv, H16, n, NT1);
  k_gather128<<<2048, 256, 0, stream>>>(H16, offsets, csr_src, dinv, b1,
                                        hprime, n);

  // --- layer 2: H2s = (h'@W2)*dinv (fp16) ; gather -> d_out ---
  k_gemm_mfma<__half, 64><<<512, 256, 0, stream>>>(hprime, W2, dinv, H16, n, NT2);
  k_gather64<<<2048, 256, 0, stream>>>(H16, offsets, csr_src, dinv, b2,
                                       out, n);
}

// Round 14
// 326.105 us; speedup vs baseline: 1.0908x; 1.0908x over previous
//
#include <hip/hip_runtime.h>
#include <hip/hip_fp16.h>
#include <cstdint>
#include <cstddef>

// ---------------------------------------------------------------------------
// 2-layer GCN (PyG GCNConv semantics) on MI355X.
// Round 14: revert to round-12 pipeline (round-13 src-sort was null), then
// split layer-1 gather into two 64-ch half-gathers (12.8MB working set each,
// higher L2 hit rate at the measured ~3TB/s random-fill ceiling).
// H1 and h' stored as two [N][64] fp16 halves; gemm2 reads split A.
// ---------------------------------------------------------------------------

#define BSHIFT 8          // 256 nodes per bucket
#define CAP    12288      // part[] capacity per bucket (mean 8184, sd ~90)

typedef _Float16 half8 __attribute__((ext_vector_type(8)));
typedef float f32x4 __attribute__((ext_vector_type(4)));

__global__ __launch_bounds__(256) void k_binit(int* __restrict__ bktcur, int nbkt) {
  int b = blockIdx.x * 256 + threadIdx.x;
  if (b < nbkt) bktcur[b] = b * CAP;
}

// Partition edges by dst-bucket into fixed-capacity windows of part[]
// (packed (src<<8)|dst_low). Per-block LDS histogram -> one reservation/bucket.
__global__ __launch_bounds__(256) void k_part(const int* __restrict__ src,
                                              const int* __restrict__ dst,
                                              int* __restrict__ bktcur,
                                              int* __restrict__ part, int E,
                                              int nbkt) {
  __shared__ int hist[512];
  const int tid = threadIdx.x;
  const int e0 = blockIdx.x * 4096;
  for (int b = tid; b < nbkt; b += 256) hist[b] = 0;
  __syncthreads();
#pragma unroll
  for (int j = 0; j < 16; ++j) {
    const int e = e0 + j * 256 + tid;
    if (e < E) atomicAdd(&hist[dst[e] >> BSHIFT], 1);
  }
  __syncthreads();
  for (int b = tid; b < nbkt; b += 256) {
    const int c = hist[b];
    hist[b] = c ? atomicAdd(&bktcur[b], c) : 0;  // becomes running cursor
  }
  __syncthreads();
#pragma unroll
  for (int j = 0; j < 16; ++j) {
    const int e = e0 + j * 256 + tid;
    if (e < E) {
      const int d = dst[e];
      const int bkt = d >> BSHIFT;
      const int pos = atomicAdd(&hist[bkt], 1);
      if (pos < (bkt + 1) * CAP)  // statistical impossibility guard
        part[pos] = (src[e] << BSHIFT) | (d & ((1 << BSHIFT) - 1));
    }
  }
}

// Bucket bases: exclusive scan of (bktcur[b] - b*CAP). 1 block.
__global__ __launch_bounds__(256) void k_bktscan(const int* __restrict__ bktcur,
                                                 int* __restrict__ bktbase,
                                                 int* __restrict__ offsets, int n,
                                                 int E, int nbkt) {
  __shared__ int sc[512];
  const int t = threadIdx.x;
  sc[t] = (t < nbkt) ? (bktcur[t] - t * CAP) : 0;
  sc[256 + t] = (256 + t < nbkt) ? (bktcur[256 + t] - (256 + t) * CAP) : 0;
  __syncthreads();
  if (t == 0) {
    int run = 0;
    for (int b = 0; b < nbkt; ++b) {
      const int c = sc[b];
      sc[b] = run;
      run += c;
    }
    offsets[n] = E;
    bktbase[nbkt] = E;
  }
  __syncthreads();
  if (t < nbkt) bktbase[t] = sc[t];
  if (256 + t < nbkt) bktbase[256 + t] = sc[256 + t];
}

// Per bucket: LDS per-node count, LDS scan -> offsets + dinv, then compact
// scatter into final CSR slots (LDS cursors, L2-local window writes).
__global__ __launch_bounds__(256) void k_csr2(const int* __restrict__ part,
                                              const int* __restrict__ bktcur,
                                              const int* __restrict__ bktbase,
                                              int* __restrict__ offsets,
                                              int* __restrict__ csr_src,
                                              float* __restrict__ dinv, int n) {
  __shared__ int cnt[256];
  __shared__ int ts[256];
  const int b = blockIdx.x;
  const int node0 = b << BSHIFT;
  const int nn = min(256, n - node0);
  const int t = threadIdx.x;
  cnt[t] = 0;
  __syncthreads();
  const int w0p = b * CAP;
  const int w1p = min(bktcur[b], w0p + CAP);
  for (int e = w0p + t; e < w1p; e += 256)
    atomicAdd(&cnt[part[e] & ((1 << BSHIFT) - 1)], 1);
  __syncthreads();
  const int c = cnt[t];
  ts[t] = c;
  __syncthreads();
  for (int off = 1; off < 256; off <<= 1) {
    const int u = (t >= off) ? ts[t - off] : 0;
    __syncthreads();
    ts[t] += u;
    __syncthreads();
  }
  const int excl = ts[t] - c;
  const int w0 = bktbase[b];
  if (t < nn) {
    offsets[node0 + t] = w0 + excl;
    dinv[node0 + t] = rsqrtf((float)c + 1.0f);
  }
  cnt[t] = w0 + excl;  // becomes cursor
  __syncthreads();
  for (int e = w0p + t; e < w1p; e += 256) {
    const int p = part[e];
    const int pos = atomicAdd(&cnt[p & ((1 << BSHIFT) - 1)], 1);
    csr_src[pos] = p >> BSHIFT;
  }
}

// ---------------------------------------------------------------------------
// Layer-1 MFMA GEMM: (x[N,128] @ W1[128,128]) * dinv -> two fp16 halves
// Hlo[N][64] (cols 0-63), Hhi[N][64] (cols 64-127). Round-12 core.
// ---------------------------------------------------------------------------
__global__ __launch_bounds__(256) void k_gemm1(const float* __restrict__ A,
                                               const float* __restrict__ W,
                                               const float* __restrict__ dinv,
                                               __half* __restrict__ Hlo,
                                               __half* __restrict__ Hhi,
                                               int N, int ntiles) {
  constexpr int COLS = 128;
  constexpr int RPT = 32;  // 2 row-waves x 16
  __shared__ _Float16 Wt[128 * COLS];
  __shared__ _Float16 Lb[4][16][72];
  const int tid = threadIdx.x;
  const int w = tid >> 6;
  const int l = tid & 63;

  for (int f = tid; f < (128 * COLS) / 4; f += 256) {
    const int k = f / (COLS / 4);
    const int c4 = (f % (COLS / 4)) * 4;
    const float4 wv = *reinterpret_cast<const float4*>(W + (size_t)k * COLS + c4);
#pragma unroll
    for (int j = 0; j < 4; ++j) {
      const int cc = c4 + j;
      Wt[(cc * 128 + k) ^ ((cc & 7) << 3)] = (_Float16)(&wv.x)[j];
    }
  }
  __syncthreads();

  const int colw = (w >> 1) * 64;
  const int rw = w & 1;
  const int koff = (l >> 4) * 8;

  half8 bf[4][4];
#pragma unroll
  for (int t = 0; t < 4; ++t)
#pragma unroll
    for (int s = 0; s < 4; ++s) {
      const int cc = colw + 16 * t + (l & 15);
      const int kk = 32 * s + koff;
      bf[t][s] =
          *reinterpret_cast<const half8*>(&Wt[(cc * 128 + kk) ^ ((cc & 7) << 3)]);
    }

  for (int tile = blockIdx.x; tile < ntiles; tile += gridDim.x) {
    const int row = tile * RPT + rw * 16 + (l & 15);
    const int rowc = (row < N) ? row : (N - 1);
    f32x4 acc[4];
#pragma unroll
    for (int t = 0; t < 4; ++t) acc[t] = (f32x4){0.f, 0.f, 0.f, 0.f};

#pragma unroll
    for (int s = 0; s < 4; ++s) {
      half8 af;
      const float* ap = A + (size_t)rowc * 128 + 32 * s + koff;
      const float4 a0 = *reinterpret_cast<const float4*>(ap);
      const float4 a1 = *reinterpret_cast<const float4*>(ap + 4);
#pragma unroll
      for (int j = 0; j < 4; ++j) {
        af[j] = (_Float16)(&a0.x)[j];
        af[4 + j] = (_Float16)(&a1.x)[j];
      }
#pragma unroll
      for (int t = 0; t < 4; ++t)
        acc[t] = __builtin_amdgcn_mfma_f32_16x16x32_f16(af, bf[t][s], acc[t],
                                                        0, 0, 0);
    }

    const int rbase = tile * RPT + rw * 16 + (l >> 4) * 4;
    float dr[4];
#pragma unroll
    for (int r = 0; r < 4; ++r) {
      const int rr = rbase + r;
      dr[r] = (rr < N) ? dinv[rr] : 0.f;
    }

#pragma unroll
    for (int t = 0; t < 4; ++t)
#pragma unroll
      for (int r = 0; r < 4; ++r)
        Lb[w][(l >> 4) * 4 + r][16 * t + (l & 15)] = (_Float16)(acc[t][r] * dr[r]);
    const int orow = tile * RPT + rw * 16 + (l & 15);
    if (orow < N) {
      const int ch = (l >> 4) * 16;
      const half8 v0 = *reinterpret_cast<const half8*>(&Lb[w][l & 15][ch]);
      const half8 v1 = *reinterpret_cast<const half8*>(&Lb[w][l & 15][ch + 8]);
      __half* base = (colw == 0) ? Hlo : Hhi;
      __half* hp = base + (size_t)orow * 64 + ch;
      *reinterpret_cast<half8*>(hp) = v0;
      *reinterpret_cast<half8*>(hp + 8) = v1;
    }
  }
}

// ---------------------------------------------------------------------------
// Layer-2 MFMA GEMM: ((hlo|hhi)[N,128] @ W2[128,64]) * dinv -> H2[N][64] fp16.
// A is split into two fp16 halves. Round-12 COLS=64 core.
// ---------------------------------------------------------------------------
__global__ __launch_bounds__(256) void k_gemm2(const __half* __restrict__ Alo,
                                               const __half* __restrict__ Ahi,
                                               const float* __restrict__ W,
                                               const float* __restrict__ dinv,
                                               __half* __restrict__ Hout,
                                               int N, int ntiles) {
  constexpr int COLS = 64;
  constexpr int RPT = 64;  // 4 row-waves x 16
  __shared__ _Float16 Wt[128 * COLS];
  __shared__ _Float16 Lb[4][16][72];
  const int tid = threadIdx.x;
  const int w = tid >> 6;
  const int l = tid & 63;

  for (int f = tid; f < (128 * COLS) / 4; f += 256) {
    const int k = f / (COLS / 4);
    const int c4 = (f % (COLS / 4)) * 4;
    const float4 wv = *reinterpret_cast<const float4*>(W + (size_t)k * COLS + c4);
#pragma unroll
    for (int j = 0; j < 4; ++j) {
      const int cc = c4 + j;
      Wt[(cc * 128 + k) ^ ((cc & 7) << 3)] = (_Float16)(&wv.x)[j];
    }
  }
  __syncthreads();

  const int rw = w;
  const int koff = (l >> 4) * 8;

  half8 bf[4][4];
#pragma unroll
  for (int t = 0; t < 4; ++t)
#pragma unroll
    for (int s = 0; s < 4; ++s) {
      const int cc = 16 * t + (l & 15);
      const int kk = 32 * s + koff;
      bf[t][s] =
          *reinterpret_cast<const half8*>(&Wt[(cc * 128 + kk) ^ ((cc & 7) << 3)]);
    }

  for (int tile = blockIdx.x; tile < ntiles; tile += gridDim.x) {
    const int row = tile * RPT + rw * 16 + (l & 15);
    const int rowc = (row < N) ? row : (N - 1);
    f32x4 acc[4];
#pragma unroll
    for (int t = 0; t < 4; ++t) acc[t] = (f32x4){0.f, 0.f, 0.f, 0.f};

#pragma unroll
    for (int s = 0; s < 4; ++s) {
      const __half* ab = (s < 2) ? Alo : Ahi;
      const int kk = (s & 1) * 32 + koff;
      const half8 af =
          *reinterpret_cast<const half8*>(ab + (size_t)rowc * 64 + kk);
#pragma unroll
      for (int t = 0; t < 4; ++t)
        acc[t] = __builtin_amdgcn_mfma_f32_16x16x32_f16(af, bf[t][s], acc[t],
                                                        0, 0, 0);
    }

    const int rbase = tile * RPT + rw * 16 + (l >> 4) * 4;
    float dr[4];
#pragma unroll
    for (int r = 0; r < 4; ++r) {
      const int rr = rbase + r;
      dr[r] = (rr < N) ? dinv[rr] : 0.f;
    }

#pragma unroll
    for (int t = 0; t < 4; ++t)
#pragma unroll
      for (int r = 0; r < 4; ++r)
        Lb[w][(l >> 4) * 4 + r][16 * t + (l & 15)] = (_Float16)(acc[t][r] * dr[r]);
    const int orow = tile * RPT + rw * 16 + (l & 15);
    if (orow < N) {
      const int ch = (l >> 4) * 16;
      const half8 v0 = *reinterpret_cast<const half8*>(&Lb[w][l & 15][ch]);
      const half8 v1 = *reinterpret_cast<const half8*>(&Lb[w][l & 15][ch + 8]);
      __half* hp = Hout + (size_t)orow * 64 + ch;
      *reinterpret_cast<half8*>(hp) = v0;
      *reinterpret_cast<half8*>(hp + 8) = v1;
    }
  }
}

// ---------------------------------------------------------------------------
// 64-ch CSR gather over pre-scaled fp16 H (Hs = h*dinv), fp32 accumulate.
//   row_i = dinv[i] * (sum_{s in N(i)} Hs[s] + Hs[i]) + bias ; relu
// One wave/node: 8 edge slots x 8 channel lanes (16B loads); 2x unrolled.
// OUT16=1 -> fp16 output (layer-1 halves); OUT16=0 -> fp32 (final out).
// ---------------------------------------------------------------------------
template <int OUT16>
__global__ __launch_bounds__(256) void k_gather64t(
    const __half* __restrict__ H, const int* __restrict__ offsets,
    const int* __restrict__ csr_src, const float* __restrict__ dinv,
    const float* __restrict__ bias, void* __restrict__ outv, int N) {
  const int lane = threadIdx.x & 63;
  const int g = lane >> 3;  // 0..7 edge slot
  const int sl = lane & 7;  // 0..7 channel block (8 ch)
  int w = (blockIdx.x * 256 + threadIdx.x) >> 6;
  const int nw = (gridDim.x * 256) >> 6;
  for (int i = w; i < N; i += nw) {
    const int beg = offsets[i];
    const int end = offsets[i + 1];
    float acc[8];
    {
      const float vf = (g == 0) ? 1.f : 0.f;
      const float4 ha = *reinterpret_cast<const float4*>(H + (size_t)i * 64 + sl * 8);
      const __half2* pa = reinterpret_cast<const __half2*>(&ha);
#pragma unroll
      for (int q = 0; q < 4; ++q) {
        const float2 fa = __half22float2(pa[q]);
        acc[q * 2] = vf * fa.x;
        acc[q * 2 + 1] = vf * fa.y;
      }
    }
    int base = beg;
    for (; base + 16 <= end; base += 16) {
      const int s0 = __builtin_nontemporal_load(csr_src + base + g);
      const int s1 = __builtin_nontemporal_load(csr_src + base + 8 + g);
      const float4 h0 = *reinterpret_cast<const float4*>(H + (size_t)s0 * 64 + sl * 8);
      const float4 h1 = *reinterpret_cast<const float4*>(H + (size_t)s1 * 64 + sl * 8);
      const __half2* p0 = reinterpret_cast<const __half2*>(&h0);
      const __half2* p1 = reinterpret_cast<const __half2*>(&h1);
#pragma unroll
      for (int q = 0; q < 4; ++q) {
        const float2 f0 = __half22float2(p0[q]);
        const float2 f1 = __half22float2(p1[q]);
        acc[q * 2] += f0.x + f1.x;
        acc[q * 2 + 1] += f0.y + f1.y;
      }
    }
    for (; base < end; base += 8) {
      const int e = base + g;
      const bool v = e < end;
      const int s = v ? __builtin_nontemporal_load(csr_src + e) : i;
      const float vf = v ? 1.f : 0.f;
      const float4 ha = *reinterpret_cast<const float4*>(H + (size_t)s * 64 + sl * 8);
      const __half2* pa = reinterpret_cast<const __half2*>(&ha);
#pragma unroll
      for (int q = 0; q < 4; ++q) {
        const float2 fa = __half22float2(pa[q]);
        acc[q * 2] = fmaf(vf, fa.x, acc[q * 2]);
        acc[q * 2 + 1] = fmaf(vf, fa.y, acc[q * 2 + 1]);
      }
    }
#pragma unroll
    for (int j = 0; j < 8; ++j) {
      float a = acc[j];
      a += __shfl_xor(a, 8);
      a += __shfl_xor(a, 16);
      a += __shfl_xor(a, 32);
      acc[j] = a;
    }
    if (g == 0) {
      const float di = dinv[i];
      if constexpr (OUT16) {
        __half2 ov[4];
#pragma unroll
        for (int q = 0; q < 4; ++q) {
          const float2 bv = *reinterpret_cast<const float2*>(bias + sl * 8 + q * 2);
          ov[q] = __floats2half2_rn(fmaxf(fmaf(di, acc[q * 2], bv.x), 0.f),
                                    fmaxf(fmaf(di, acc[q * 2 + 1], bv.y), 0.f));
        }
        __half* op = (__half*)outv + (size_t)i * 64 + sl * 8;
        *reinterpret_cast<float4*>(op) = *reinterpret_cast<const float4*>(&ov[0]);
      } else {
        float* op = (float*)outv + (size_t)i * 64 + sl * 8;
        const float4 b0 = *reinterpret_cast<const float4*>(bias + sl * 8);
        const float4 b1 = *reinterpret_cast<const float4*>(bias + sl * 8 + 4);
        float4 o;
        o.x = fmaxf(fmaf(di, acc[0], b0.x), 0.f);
        o.y = fmaxf(fmaf(di, acc[1], b0.y), 0.f);
        o.z = fmaxf(fmaf(di, acc[2], b0.z), 0.f);
        o.w = fmaxf(fmaf(di, acc[3], b0.w), 0.f);
        *reinterpret_cast<float4*>(op) = o;
        o.x = fmaxf(fmaf(di, acc[4], b1.x), 0.f);
        o.y = fmaxf(fmaf(di, acc[5], b1.y), 0.f);
        o.z = fmaxf(fmaf(di, acc[6], b1.z), 0.f);
        o.w = fmaxf(fmaf(di, acc[7], b1.w), 0.f);
        *reinterpret_cast<float4*>(op + 4) = o;
      }
    }
  }
}

extern "C" void kernel_launch(void* const* d_in, const int* in_sizes, int n_in,
                              void* d_out, int out_size, void* d_ws,
                              size_t ws_size, hipStream_t stream) {
  const float* x  = (const float*)d_in[0];
  const int*   ei = (const int*)d_in[1];
  const float* W1 = (const float*)d_in[2];
  const float* b1 = (const float*)d_in[3];
  const float* W2 = (const float*)d_in[4];
  const float* b2 = (const float*)d_in[5];

  const int IN  = 128;
  const int n   = in_sizes[0] / IN;   // 100000
  const int E   = in_sizes[1] / 2;    // 3200000
  const int* srcv = ei;
  const int* dstv = ei + E;
  float* out = (float*)d_out;

  const int NBKT = (n + 255) >> BSHIFT;    // buckets (391)
  const int NCHK = (E + 4095) / 4096;      // partition chunks (782)
  const int NT1  = (n + 31) / 32;          // layer-1 tiles (3125)
  const int NT2  = (n + 63) / 64;          // layer-2 tiles (1563)

  // Workspace (~65 MB). part[] aliases hplo/hphi (contiguous, dead until
  // the half-gathers write them).
  char* p = (char*)d_ws;
  auto take = [&](size_t bytes) {
    char* r = p;
    p += (bytes + 255) & ~(size_t)255;
    return r;
  };
  float*  dinv    = (float*)take((size_t)n * 4);
  int*    offsets = (int*)take((size_t)(n + 1) * 4);
  int*    bktbase = (int*)take(512 * 4);
  int*    bktcur  = (int*)take(512 * 4);
  int*    csr_src = (int*)take((size_t)E * 4);           // 12.8 MB
  __half* Hlo     = (__half*)take((size_t)n * 64 * 2);   // 12.8 MB (H1 lo; later H2)
  __half* Hhi     = (__half*)take((size_t)n * 64 * 2);   // 12.8 MB (H1 hi)
  __half* hplo    = (__half*)take((size_t)n * 64 * 2);   // 12.8 MB (h' lo)
  __half* hphi    = (__half*)take((size_t)n * 64 * 2);   // 12.8 MB (h' hi)
  int*    part    = (int*)hplo;                          // 19.2 MB alias

  // --- single-pass CSR build (round 12) ---
  k_binit<<<(NBKT + 255) / 256, 256, 0, stream>>>(bktcur, NBKT);
  k_part<<<NCHK, 256, 0, stream>>>(srcv, dstv, bktcur, part, E, NBKT);
  k_bktscan<<<1, 256, 0, stream>>>(bktcur, bktbase, offsets, n, E, NBKT);
  k_csr2<<<NBKT, 256, 0, stream>>>(part, bktcur, bktbase, offsets, csr_src,
                                   dinv, n);

  // --- layer 1: H1s = (x@W1)*dinv (two fp16 halves) ; two half-gathers ---
  k_gemm1<<<512, 256, 0, stream>>>(x, W1, dinv, Hlo, Hhi, n, NT1);
  k_gather64t<1><<<25000, 256, 0, stream>>>(Hlo, offsets, csr_src, dinv, b1,
                                            hplo, n);
  k_gather64t<1><<<25000, 256, 0, stream>>>(Hhi, offsets, csr_src, dinv,
                                            b1 + 64, hphi, n);

  // --- layer 2: H2s = (h'@W2)*dinv (fp16, reuse Hlo) ; gather -> d_out ---
  k_gemm2<<<512, 256, 0, stream>>>(hplo, hphi, W2, dinv, Hlo, n, NT2);
  k_gather64t<0><<<25000, 256, 0, stream>>>(Hlo, offsets, csr_src, dinv, b2,
                                            out, n);
}

// Round 15
// 298.578 us; speedup vs baseline: 1.1913x; 1.0922x over previous
//
#include <hip/hip_runtime.h>
#include <hip/hip_fp16.h>
#include <cstdint>
#include <cstddef>

// ---------------------------------------------------------------------------
// 2-layer GCN (PyG GCNConv semantics) on MI355X.
// Round 15: round-12 pipeline (best: 316us) + k_part3: in-LDS reorder so the
// windowed partition writes are contiguous runs (radix-scatter trick).
// ---------------------------------------------------------------------------

#define BSHIFT 8          // 256 nodes per bucket
#define CAP    12288      // part[] capacity per bucket (mean 8184, sd ~90)

typedef _Float16 half8 __attribute__((ext_vector_type(8)));
typedef float f32x4 __attribute__((ext_vector_type(4)));

__global__ __launch_bounds__(256) void k_binit(int* __restrict__ bktcur, int nbkt) {
  int b = blockIdx.x * 256 + threadIdx.x;
  if (b < nbkt) bktcur[b] = b * CAP;
}

// Partition with in-LDS reorder: hist -> local scan -> global reservation ->
// LDS scatter -> linear write-out (contiguous per-bucket runs).
__global__ __launch_bounds__(256) void k_part3(const int* __restrict__ src,
                                               const int* __restrict__ dst,
                                               int* __restrict__ bktcur,
                                               int* __restrict__ part, int E,
                                               int nbkt) {
  __shared__ int vals[4096];
  __shared__ unsigned short bid[4096];
  __shared__ int hist[512];   // counts -> local running cursor
  __shared__ int lbase[512];  // local exclusive base
  __shared__ int gbase[512];  // global reserved base
  const int tid = threadIdx.x;
  const int e0 = blockIdx.x * 4096;
  const int ecnt = min(4096, E - e0);
  for (int b = tid; b < nbkt; b += 256) hist[b] = 0;
  __syncthreads();

  int eb[16], ev[16];
#pragma unroll
  for (int j = 0; j < 16; ++j) {
    const int e = e0 + j * 256 + tid;
    eb[j] = -1;
    ev[j] = 0;
    if (e < E) {
      const int d = dst[e];
      eb[j] = d >> BSHIFT;
      ev[j] = (src[e] << BSHIFT) | (d & ((1 << BSHIFT) - 1));
      atomicAdd(&hist[eb[j]], 1);
    }
  }
  __syncthreads();

  if (tid == 0) {  // serial exclusive scan over nbkt (<1us, overlapped)
    int run = 0;
    for (int b = 0; b < nbkt; ++b) {
      const int c = hist[b];
      lbase[b] = run;
      run += c;
    }
  }
  __syncthreads();
  for (int b = tid; b < nbkt; b += 256) {
    const int c = hist[b];
    gbase[b] = c ? atomicAdd(&bktcur[b], c) : 0;
    hist[b] = lbase[b];  // becomes local cursor
  }
  __syncthreads();

#pragma unroll
  for (int j = 0; j < 16; ++j) {
    if (eb[j] >= 0) {
      const int lpos = atomicAdd(&hist[eb[j]], 1);
      vals[lpos] = ev[j];
      bid[lpos] = (unsigned short)eb[j];
    }
  }
  __syncthreads();

  for (int s = tid; s < ecnt; s += 256) {
    const int b = bid[s];
    const int gpos = gbase[b] + (s - lbase[b]);
    if (gpos < (b + 1) * CAP)  // statistical impossibility guard
      part[gpos] = vals[s];
  }
}

// Bucket bases: exclusive scan of (bktcur[b] - b*CAP). 1 block.
__global__ __launch_bounds__(256) void k_bktscan(const int* __restrict__ bktcur,
                                                 int* __restrict__ bktbase,
                                                 int* __restrict__ offsets, int n,
                                                 int E, int nbkt) {
  __shared__ int sc[512];
  const int t = threadIdx.x;
  sc[t] = (t < nbkt) ? (bktcur[t] - t * CAP) : 0;
  sc[256 + t] = (256 + t < nbkt) ? (bktcur[256 + t] - (256 + t) * CAP) : 0;
  __syncthreads();
  if (t == 0) {
    int run = 0;
    for (int b = 0; b < nbkt; ++b) {
      const int c = sc[b];
      sc[b] = run;
      run += c;
    }
    offsets[n] = E;
    bktbase[nbkt] = E;
  }
  __syncthreads();
  if (t < nbkt) bktbase[t] = sc[t];
  if (256 + t < nbkt) bktbase[256 + t] = sc[256 + t];
}

// Per bucket: LDS per-node count, LDS scan -> offsets + dinv, then compact
// scatter into final CSR slots (LDS cursors, L2-local window writes).
__global__ __launch_bounds__(256) void k_csr2(const int* __restrict__ part,
                                              const int* __restrict__ bktcur,
                                              const int* __restrict__ bktbase,
                                              int* __restrict__ offsets,
                                              int* __restrict__ csr_src,
                                              float* __restrict__ dinv, int n) {
  __shared__ int cnt[256];
  __shared__ int ts[256];
  const int b = blockIdx.x;
  const int node0 = b << BSHIFT;
  const int nn = min(256, n - node0);
  const int t = threadIdx.x;
  cnt[t] = 0;
  __syncthreads();
  const int w0p = b * CAP;
  const int w1p = min(bktcur[b], w0p + CAP);
  for (int e = w0p + t; e < w1p; e += 256)
    atomicAdd(&cnt[part[e] & ((1 << BSHIFT) - 1)], 1);
  __syncthreads();
  const int c = cnt[t];
  ts[t] = c;
  __syncthreads();
  for (int off = 1; off < 256; off <<= 1) {
    const int u = (t >= off) ? ts[t - off] : 0;
    __syncthreads();
    ts[t] += u;
    __syncthreads();
  }
  const int excl = ts[t] - c;
  const int w0 = bktbase[b];
  if (t < nn) {
    offsets[node0 + t] = w0 + excl;
    dinv[node0 + t] = rsqrtf((float)c + 1.0f);
  }
  cnt[t] = w0 + excl;  // becomes cursor
  __syncthreads();
  for (int e = w0p + t; e < w1p; e += 256) {
    const int p = part[e];
    const int pos = atomicAdd(&cnt[p & ((1 << BSHIFT) - 1)], 1);
    csr_src[pos] = p >> BSHIFT;
  }
}

// ---------------------------------------------------------------------------
// MFMA fp16 GEMM: Hout[N,COLS](fp16) = (A[N,128] @ W[128,COLS]) * dinv[row].
// TA = float (in-kernel cvt to fp16) or __half. f32 accumulate; dinv applied
// in f32 before the fp16 convert.
// ---------------------------------------------------------------------------
template <typename TA, int COLS>
__global__ __launch_bounds__(256) void k_gemm_mfma(const TA* __restrict__ A,
                                                   const float* __restrict__ W,
                                                   const float* __restrict__ dinv,
                                                   __half* __restrict__ Hout,
                                                   int N, int ntiles) {
  constexpr int RW = (COLS == 128) ? 2 : 4;  // row-waves per tile
  constexpr int RPT = RW * 16;               // rows per tile
  __shared__ _Float16 Wt[128 * COLS];
  __shared__ _Float16 Lb[4][16][72];
  const int tid = threadIdx.x;
  const int w = tid >> 6;
  const int l = tid & 63;

  // stage W^T fp16 swizzled: Wt[(c*128+k) ^ ((c&7)<<3)]
  for (int f = tid; f < (128 * COLS) / 4; f += 256) {
    const int k = f / (COLS / 4);
    const int c4 = (f % (COLS / 4)) * 4;
    const float4 wv = *reinterpret_cast<const float4*>(W + (size_t)k * COLS + c4);
#pragma unroll
    for (int j = 0; j < 4; ++j) {
      const int cc = c4 + j;
      Wt[(cc * 128 + k) ^ ((cc & 7) << 3)] = (_Float16)(&wv.x)[j];
    }
  }
  __syncthreads();

  const int colw = (COLS == 128) ? (w >> 1) * 64 : 0;
  const int rw = (COLS == 128) ? (w & 1) : w;
  const int koff = (l >> 4) * 8;

  // preload B fragments
  half8 bf[4][4];
#pragma unroll
  for (int t = 0; t < 4; ++t)
#pragma unroll
    for (int s = 0; s < 4; ++s) {
      const int cc = colw + 16 * t + (l & 15);
      const int kk = 32 * s + koff;
      bf[t][s] =
          *reinterpret_cast<const half8*>(&Wt[(cc * 128 + kk) ^ ((cc & 7) << 3)]);
    }

  for (int tile = blockIdx.x; tile < ntiles; tile += gridDim.x) {
    const int row = tile * RPT + rw * 16 + (l & 15);
    const int rowc = (row < N) ? row : (N - 1);
    f32x4 acc[4];
#pragma unroll
    for (int t = 0; t < 4; ++t) acc[t] = (f32x4){0.f, 0.f, 0.f, 0.f};

#pragma unroll
    for (int s = 0; s < 4; ++s) {
      half8 af;
      if constexpr (sizeof(TA) == 4) {
        const float* ap = (const float*)A + (size_t)rowc * 128 + 32 * s + koff;
        const float4 a0 = *reinterpret_cast<const float4*>(ap);
        const float4 a1 = *reinterpret_cast<const float4*>(ap + 4);
#pragma unroll
        for (int j = 0; j < 4; ++j) {
          af[j] = (_Float16)(&a0.x)[j];
          af[4 + j] = (_Float16)(&a1.x)[j];
        }
      } else {
        af = *reinterpret_cast<const half8*>((const __half*)A +
                                             (size_t)rowc * 128 + 32 * s + koff);
      }
#pragma unroll
      for (int t = 0; t < 4; ++t)
        acc[t] = __builtin_amdgcn_mfma_f32_16x16x32_f16(af, bf[t][s], acc[t],
                                                        0, 0, 0);
    }

    // dinv scaling (f32): C/D row = tile*RPT + rw*16 + (l>>4)*4 + r
    const int rbase = tile * RPT + rw * 16 + (l >> 4) * 4;
    float dr[4];
#pragma unroll
    for (int r = 0; r < 4; ++r) {
      const int rr = rbase + r;
      dr[r] = (rr < N) ? dinv[rr] : 0.f;
    }

#pragma unroll
    for (int t = 0; t < 4; ++t)
#pragma unroll
      for (int r = 0; r < 4; ++r)
        Lb[w][(l >> 4) * 4 + r][16 * t + (l & 15)] = (_Float16)(acc[t][r] * dr[r]);
    const int orow = tile * RPT + rw * 16 + (l & 15);
    if (orow < N) {
      const int ch = (l >> 4) * 16;
      const half8 v0 = *reinterpret_cast<const half8*>(&Lb[w][l & 15][ch]);
      const half8 v1 = *reinterpret_cast<const half8*>(&Lb[w][l & 15][ch + 8]);
      __half* hp = Hout + (size_t)orow * COLS + colw + ch;
      *reinterpret_cast<half8*>(hp) = v0;
      *reinterpret_cast<half8*>(hp + 8) = v1;
    }
  }
}

// ---------------------------------------------------------------------------
// Wide CSR gather over pre-scaled H (Hs = h*dinv, fp16), fp32 accumulate.
//   out[i] = relu( dinv[i] * (sum Hs[s] + Hs[i]) + bias )
// One wave per node; 8 edge slots x 8 channel-block lanes; 2x unrolled main
// loop (no masking), fmaf(vf,..) masked tail. No per-edge dinv load.
// ---------------------------------------------------------------------------
__global__ __launch_bounds__(256) void k_gather128(
    const __half* __restrict__ H, const int* __restrict__ offsets,
    const int* __restrict__ csr_src, const float* __restrict__ dinv,
    const float* __restrict__ bias, __half* __restrict__ out, int N) {
  const int lane = threadIdx.x & 63;
  const int g = lane >> 3;  // 0..7 edge slot
  const int sl = lane & 7;  // 0..7 channel block (16 ch)
  int w = (blockIdx.x * 256 + threadIdx.x) >> 6;
  const int nw = (gridDim.x * 256) >> 6;
  for (int i = w; i < N; i += nw) {
    const int beg = offsets[i];
    const int end = offsets[i + 1];
    float acc[16];
    {
      const float vf = (g == 0) ? 1.f : 0.f;
      const float4 ha = *reinterpret_cast<const float4*>(H + (size_t)i * 128 + sl * 16);
      const float4 hb = *reinterpret_cast<const float4*>(H + (size_t)i * 128 + sl * 16 + 8);
      const __half2* pa = reinterpret_cast<const __half2*>(&ha);
      const __half2* pb = reinterpret_cast<const __half2*>(&hb);
#pragma unroll
      for (int q = 0; q < 4; ++q) {
        const float2 fa = __half22float2(pa[q]);
        const float2 fb = __half22float2(pb[q]);
        acc[q * 2] = vf * fa.x;
        acc[q * 2 + 1] = vf * fa.y;
        acc[8 + q * 2] = vf * fb.x;
        acc[8 + q * 2 + 1] = vf * fb.y;
      }
    }
    int base = beg;
    for (; base + 16 <= end; base += 16) {  // full groups: no masking
      const int s0 = __builtin_nontemporal_load(csr_src + base + g);
      const int s1 = __builtin_nontemporal_load(csr_src + base + 8 + g);
      const float4 h0a = *reinterpret_cast<const float4*>(H + (size_t)s0 * 128 + sl * 16);
      const float4 h0b = *reinterpret_cast<const float4*>(H + (size_t)s0 * 128 + sl * 16 + 8);
      const float4 h1a = *reinterpret_cast<const float4*>(H + (size_t)s1 * 128 + sl * 16);
      const float4 h1b = *reinterpret_cast<const float4*>(H + (size_t)s1 * 128 + sl * 16 + 8);
      const __half2* p0a = reinterpret_cast<const __half2*>(&h0a);
      const __half2* p0b = reinterpret_cast<const __half2*>(&h0b);
      const __half2* p1a = reinterpret_cast<const __half2*>(&h1a);
      const __half2* p1b = reinterpret_cast<const __half2*>(&h1b);
#pragma unroll
      for (int q = 0; q < 4; ++q) {
        const float2 f0a = __half22float2(p0a[q]);
        const float2 f0b = __half22float2(p0b[q]);
        const float2 f1a = __half22float2(p1a[q]);
        const float2 f1b = __half22float2(p1b[q]);
        acc[q * 2] += f0a.x + f1a.x;
        acc[q * 2 + 1] += f0a.y + f1a.y;
        acc[8 + q * 2] += f0b.x + f1b.x;
        acc[8 + q * 2 + 1] += f0b.y + f1b.y;
      }
    }
    for (; base < end; base += 8) {  // masked tail
      const int e = base + g;
      const bool v = e < end;
      const int s = v ? __builtin_nontemporal_load(csr_src + e) : i;
      const float vf = v ? 1.f : 0.f;
      const float4 ha = *reinterpret_cast<const float4*>(H + (size_t)s * 128 + sl * 16);
      const float4 hb = *reinterpret_cast<const float4*>(H + (size_t)s * 128 + sl * 16 + 8);
      const __half2* pa = reinterpret_cast<const __half2*>(&ha);
      const __half2* pb = reinterpret_cast<const __half2*>(&hb);
#pragma unroll
      for (int q = 0; q < 4; ++q) {
        const float2 fa = __half22float2(pa[q]);
        const float2 fb = __half22float2(pb[q]);
        acc[q * 2] = fmaf(vf, fa.x, acc[q * 2]);
        acc[q * 2 + 1] = fmaf(vf, fa.y, acc[q * 2 + 1]);
        acc[8 + q * 2] = fmaf(vf, fb.x, acc[8 + q * 2]);
        acc[8 + q * 2 + 1] = fmaf(vf, fb.y, acc[8 + q * 2 + 1]);
      }
    }
#pragma unroll
    for (int j = 0; j < 16; ++j) {
      float a = acc[j];
      a += __shfl_xor(a, 8);
      a += __shfl_xor(a, 16);
      a += __shfl_xor(a, 32);
      acc[j] = a;
    }
    if (g == 0) {
      const float di = dinv[i];
      __half2 ov[8];
#pragma unroll
      for (int q = 0; q < 8; ++q) {
        const float2 bv = *reinterpret_cast<const float2*>(bias + sl * 16 + q * 2);
        ov[q] = __floats2half2_rn(fmaxf(fmaf(di, acc[q * 2], bv.x), 0.f),
                                  fmaxf(fmaf(di, acc[q * 2 + 1], bv.y), 0.f));
      }
      __half* op = out + (size_t)i * 128 + sl * 16;
      *reinterpret_cast<float4*>(op) = *reinterpret_cast<const float4*>(&ov[0]);
      *reinterpret_cast<float4*>(op + 8) = *reinterpret_cast<const float4*>(&ov[4]);
    }
  }
}

__global__ __launch_bounds__(256) void k_gather64(
    const __half* __restrict__ H, const int* __restrict__ offsets,
    const int* __restrict__ csr_src, const float* __restrict__ dinv,
    const float* __restrict__ bias, float* __restrict__ out, int N) {
  const int lane = threadIdx.x & 63;
  const int g = lane >> 3;  // 0..7 edge slot
  const int sl = lane & 7;  // 0..7 channel block (8 ch)
  int w = (blockIdx.x * 256 + threadIdx.x) >> 6;
  const int nw = (gridDim.x * 256) >> 6;
  for (int i = w; i < N; i += nw) {
    const int beg = offsets[i];
    const int end = offsets[i + 1];
    float acc[8];
    {
      const float vf = (g == 0) ? 1.f : 0.f;
      const float4 ha = *reinterpret_cast<const float4*>(H + (size_t)i * 64 + sl * 8);
      const __half2* pa = reinterpret_cast<const __half2*>(&ha);
#pragma unroll
      for (int q = 0; q < 4; ++q) {
        const float2 fa = __half22float2(pa[q]);
        acc[q * 2] = vf * fa.x;
        acc[q * 2 + 1] = vf * fa.y;
      }
    }
    int base = beg;
    for (; base + 16 <= end; base += 16) {
      const int s0 = __builtin_nontemporal_load(csr_src + base + g);
      const int s1 = __builtin_nontemporal_load(csr_src + base + 8 + g);
      const float4 h0 = *reinterpret_cast<const float4*>(H + (size_t)s0 * 64 + sl * 8);
      const float4 h1 = *reinterpret_cast<const float4*>(H + (size_t)s1 * 64 + sl * 8);
      const __half2* p0 = reinterpret_cast<const __half2*>(&h0);
      const __half2* p1 = reinterpret_cast<const __half2*>(&h1);
#pragma unroll
      for (int q = 0; q < 4; ++q) {
        const float2 f0 = __half22float2(p0[q]);
        const float2 f1 = __half22float2(p1[q]);
        acc[q * 2] += f0.x + f1.x;
        acc[q * 2 + 1] += f0.y + f1.y;
      }
    }
    for (; base < end; base += 8) {
      const int e = base + g;
      const bool v = e < end;
      const int s = v ? __builtin_nontemporal_load(csr_src + e) : i;
      const float vf = v ? 1.f : 0.f;
      const float4 ha = *reinterpret_cast<const float4*>(H + (size_t)s * 64 + sl * 8);
      const __half2* pa = reinterpret_cast<const __half2*>(&ha);
#pragma unroll
      for (int q = 0; q < 4; ++q) {
        const float2 fa = __half22float2(pa[q]);
        acc[q * 2] = fmaf(vf, fa.x, acc[q * 2]);
        acc[q * 2 + 1] = fmaf(vf, fa.y, acc[q * 2 + 1]);
      }
    }
#pragma unroll
    for (int j = 0; j < 8; ++j) {
      float a = acc[j];
      a += __shfl_xor(a, 8);
      a += __shfl_xor(a, 16);
      a += __shfl_xor(a, 32);
      acc[j] = a;
    }
    if (g == 0) {
      const float di = dinv[i];
      float* op = out + (size_t)i * 64 + sl * 8;
      const float4 b0 = *reinterpret_cast<const float4*>(bias + sl * 8);
      const float4 b1 = *reinterpret_cast<const float4*>(bias + sl * 8 + 4);
      float4 o;
      o.x = fmaxf(fmaf(di, acc[0], b0.x), 0.f);
      o.y = fmaxf(fmaf(di, acc[1], b0.y), 0.f);
      o.z = fmaxf(fmaf(di, acc[2], b0.z), 0.f);
      o.w = fmaxf(fmaf(di, acc[3], b0.w), 0.f);
      *reinterpret_cast<float4*>(op) = o;
      o.x = fmaxf(fmaf(di, acc[4], b1.x), 0.f);
      o.y = fmaxf(fmaf(di, acc[5], b1.y), 0.f);
      o.z = fmaxf(fmaf(di, acc[6], b1.z), 0.f);
      o.w = fmaxf(fmaf(di, acc[7], b1.w), 0.f);
      *reinterpret_cast<float4*>(op + 4) = o;
    }
  }
}

extern "C" void kernel_launch(void* const* d_in, const int* in_sizes, int n_in,
                              void* d_out, int out_size, void* d_ws,
                              size_t ws_size, hipStream_t stream) {
  const float* x  = (const float*)d_in[0];
  const int*   ei = (const int*)d_in[1];
  const float* W1 = (const float*)d_in[2];
  const float* b1 = (const float*)d_in[3];
  const float* W2 = (const float*)d_in[4];
  const float* b2 = (const float*)d_in[5];

  const int IN  = 128;
  const int n   = in_sizes[0] / IN;   // 100000
  const int E   = in_sizes[1] / 2;    // 3200000
  const int* srcv = ei;
  const int* dstv = ei + E;
  float* out = (float*)d_out;

  const int NBKT = (n + 255) >> BSHIFT;    // buckets (391)
  const int NCHK = (E + 4095) / 4096;      // partition chunks (782)
  const int NT1  = (n + 31) / 32;          // layer-1 tiles (3125)
  const int NT2  = (n + 63) / 64;          // layer-2 tiles (1563)

  // Workspace (~65 MB): part[] aliases hprime (dead until gather128 writes it).
  char* p = (char*)d_ws;
  auto take = [&](size_t bytes) {
    char* r = p;
    p += (bytes + 255) & ~(size_t)255;
    return r;
  };
  float*  dinv    = (float*)take((size_t)n * 4);
  int*    offsets = (int*)take((size_t)(n + 1) * 4);
  int*    bktbase = (int*)take(512 * 4);
  int*    bktcur  = (int*)take(512 * 4);
  int*    csr_src = (int*)take((size_t)E * 4);            // 12.8 MB
  __half* H16     = (__half*)take((size_t)n * 128 * 2);   // 25.6 MB (H1s; later H2s)
  __half* hprime  = (__half*)take((size_t)n * 128 * 2);   // 25.6 MB (h' fp16)
  int*    part    = (int*)hprime;                          // 19.2 MB alias

  // --- single-pass CSR build ---
  k_binit<<<(NBKT + 255) / 256, 256, 0, stream>>>(bktcur, NBKT);
  k_part3<<<NCHK, 256, 0, stream>>>(srcv, dstv, bktcur, part, E, NBKT);
  k_bktscan<<<1, 256, 0, stream>>>(bktcur, bktbase, offsets, n, E, NBKT);
  k_csr2<<<NBKT, 256, 0, stream>>>(part, bktcur, bktbase, offsets, csr_src,
                                   dinv, n);

  // --- layer 1: H1s = (x@W1)*dinv (fp16) ; gather -> h' (fp16) ---
  k_gemm_mfma<float, 128><<<512, 256, 0, stream>>>(x, W1, dinv, H16, n, NT1);
  k_gather128<<<25000, 256, 0, stream>>>(H16, offsets, csr_src, dinv, b1,
                                         hprime, n);

  // --- layer 2: H2s = (h'@W2)*dinv (fp16) ; gather -> d_out ---
  k_gemm_mfma<__half, 64><<<512, 256, 0, stream>>>(hprime, W2, dinv, H16, n, NT2);
  k_gather64<<<25000, 256, 0, stream>>>(H16, offsets, csr_src, dinv, b2,
                                        out, n);
}